// Round 9
// baseline (610.718 us; speedup 1.0000x reference)
//
#include <hip/hip_runtime.h>

#define T_LEN 512
#define D_DIM 32
#define N_DIM 64
#define B_ALL 128
#define R_PAIR 16     // rows per block: stream A = rows 0-7, B = rows 8-15
#define M_DIM 16      // MFMA M dimension
#define HSTR 72       // ushort row stride for h planes: 16B-aligned, bank-spread

typedef short s8v __attribute__((ext_vector_type(8)));   // 8 bf16 (4 VGPRs)
typedef float f4v __attribute__((ext_vector_type(4)));   // MFMA C/D
typedef float f2v __attribute__((ext_vector_type(2)));
typedef unsigned int uint;
typedef unsigned short u16;

__device__ __forceinline__ float rcp_f(float x) {
#if __has_builtin(__builtin_amdgcn_rcpf)
    return __builtin_amdgcn_rcpf(x);
#else
    return 1.0f / x;
#endif
}
__device__ __forceinline__ float tanh_f(float x) {
    float e = __expf(2.0f * x);
    return 1.0f - 2.0f * rcp_f(e + 1.0f);
}
__device__ __forceinline__ float sig_f(float x) {
    return rcp_f(1.0f + __expf(-x));
}
__device__ __forceinline__ uint f2bf(float f) {   // fp32 -> bf16 bits, RNE
    uint u = __float_as_uint(f);
    return (u + 0x7FFFu + ((u >> 16) & 1u)) >> 16;
}
__device__ __forceinline__ s8v pack4(uint a, uint b, uint c, uint d_) {
    union { uint u[4]; s8v v; } x;
    x.u[0] = a; x.u[1] = b; x.u[2] = c; x.u[3] = d_;
    return x.v;
}

// R9: TWO-STREAM SOFTWARE PIPELINE (fixes R7's serial-pipe ceiling).
// R7/R8 counters: MfmaUtil+VALUBusy ~= 100% -> matrix phase (1086cy) and
// VALU phase (1334cy) run back-to-back; passive de-phasing (R8) decayed.
// Fix: each block = one d, TWO row-streams A(0-7)/B(8-15) sharing W/Ff/U/b
// registers (R4's VGPR-doubling defect removed). Skewed schedule per iter:
//   MFMA_A(k) | VALU_B(k-1)  -> barrier ->  MFMA_B(k) | VALU_A(k)  -> barrier
// In each half, the MFMA burst and VALU burst are INDEPENDENT in one basic
// block -> scheduler interleaves, both pipes fill concurrently (guaranteed
// ready work, unlike R4's same-step dependency). Per-SIMD totals identical
// to R7; wall -> max(VALU,MFMA) instead of sum. Grid 256 = 1 block/CU
// (Occupancy ~12% is EXPECTED). Alpha stays MFMA-folded, one-step deferred
// per stream with exact spurious-term cancellation and drains.
// NOTE: C-fold of x*U+b into MFMA C-in regressed (R5/R6) - keep acc=0.
__global__ void __launch_bounds__(256, 1)
imv_lstm_scan(const float* __restrict__ x,
              const float* __restrict__ Uj, const float* __restrict__ Ui,
              const float* __restrict__ Uf, const float* __restrict__ Uo,
              const float* __restrict__ Wj, const float* __restrict__ Wi,
              const float* __restrict__ Wf, const float* __restrict__ Wo,
              const float* __restrict__ bj, const float* __restrict__ bi_,
              const float* __restrict__ bf_, const float* __restrict__ bo,
              const float* __restrict__ Fa, const float* __restrict__ Fab,
              const float* __restrict__ Fbw, const float* __restrict__ Fbb,
              const float* __restrict__ Pw, const float* __restrict__ Pb,
              float* __restrict__ wmu, float* __restrict__ wbeta)
{
    __shared__ float sXT[T_LEN][R_PAIR];      // 32 KB, [t][r] (16 rows)
    __shared__ u16   sAHh[2][M_DIM][HSTR];    // stream A h hi bf16
    __shared__ u16   sAHl[2][M_DIM][HSTR];    // stream A h lo bf16
    __shared__ u16   sBHh[2][M_DIM][HSTR];    // stream B h hi bf16
    __shared__ u16   sBHl[2][M_DIM][HSTR];    // stream B h lo bf16
    __shared__ float sPS[R_PAIR][4];          // epilogue mu partials
    __shared__ float sPV[R_PAIR][4];          // epilogue beta partials

    const int tid  = threadIdx.x;
    const int lane = tid & 63;
    const int wg   = tid >> 6;               // 0..3 (n-group)
    const int quad = lane >> 4;              // 0..3
    const int col  = lane & 15;
    const int d    = blockIdx.x & 31;
    const int rt   = blockIdx.x >> 5;        // 0..7
    const int r0   = rt * R_PAIR;
    const int n    = wg * 16 + col;          // this lane's n
    const int mrow = quad * 4;               // first M row of lane's 2 rows
    const int rrow = quad * 2;               // first real row (per stream)

    // ---- stage x transposed: sXT[t][r], 16 rows ----
    for (int i = tid; i < R_PAIR * T_LEN; i += 256) {
        int t = i >> 4, r = i & 15;
        sXT[t][r] = x[((size_t)(r0 + r) * T_LEN + t) * D_DIM + d];
    }
    // ---- h0 = 0 (both streams, both buffers) ----
    for (int i = tid; i < 2 * M_DIM * HSTR; i += 256) {
        ((u16*)sAHh)[i] = 0; ((u16*)sAHl)[i] = 0;
        ((u16*)sBHh)[i] = 0; ((u16*)sBHl)[i] = 0;
    }

    // ---- W fragments (SHARED by both streams): Bh/Bl[gate][k-chunk] ----
    s8v Bh[4][2], Bl[4][2];
    #pragma unroll
    for (int g = 0; g < 4; ++g) {
        const float* Wg = (g == 0 ? Wj : g == 1 ? Wi : g == 2 ? Wf : Wo)
                          + d * (N_DIM * N_DIM);
        #pragma unroll
        for (int c = 0; c < 2; ++c) {
            uint hp[4], lp[4];
            #pragma unroll
            for (int jp = 0; jp < 4; ++jp) {
                float w0 = Wg[(32 * c + quad * 8 + 2 * jp + 0) * N_DIM + n];
                float w1 = Wg[(32 * c + quad * 8 + 2 * jp + 1) * N_DIM + n];
                uint u0 = __float_as_uint(w0), u1 = __float_as_uint(w1);
                uint h0b = u0 & 0xFFFF0000u, h1b = u1 & 0xFFFF0000u;
                float l0 = w0 - __uint_as_float(h0b);
                float l1 = w1 - __uint_as_float(h1b);
                hp[jp] = (u0 >> 16) | h1b;
                lp[jp] = f2bf(l0) | (f2bf(l1) << 16);
            }
            Bh[g][c] = pack4(hp[0], hp[1], hp[2], hp[3]);
            Bl[g][c] = pack4(lp[0], lp[1], lp[2], lp[3]);
        }
    }

    // ---- fan-vector B fragment (shared): col-replicated bf16(fan) ----
    s8v Ff[2];
    #pragma unroll
    for (int c = 0; c < 2; ++c) {
        uint p[4];
        #pragma unroll
        for (int jp = 0; jp < 4; ++jp) {
            float f0 = Fa[d * N_DIM + 32 * c + quad * 8 + 2 * jp + 0];
            float f1 = Fa[d * N_DIM + 32 * c + quad * 8 + 2 * jp + 1];
            p[jp] = f2bf(f0) | (f2bf(f1) << 16);
        }
        Ff[c] = pack4(p[0], p[1], p[2], p[3]);
    }

    const int dn = d * N_DIM + n;
    const float u_j = Uj[dn], u_i = Ui[dn], u_f = Uf[dn], u_o = Uo[dn];
    const float cbj = bj[dn], cbi = bi_[dn], cbf = bf_[dn], cbo = bo[dn];
    const float fab = Fab[d];

    __syncthreads();

    float cA[2] = {0.f, 0.f}, hA[2] = {0.f, 0.f}, gaA[2] = {0.f, 0.f};
    float cB[2] = {0.f, 0.f}, hB[2] = {0.f, 0.f}, gaB[2] = {0.f, 0.f};
    const float al_m1 = __expf(tanh_f(fab));
    float asA[2] = {-al_m1, -al_m1};
    float asB[2] = {-al_m1, -al_m1};

    f4v accB[4];                 // B's MFMA results pending from prev iter
    f4v afB0 = {0.f,0.f,0.f,0.f}, afB1 = {0.f,0.f,0.f,0.f};

    #pragma unroll 2
    for (int k = 0; k < T_LEN; ++k) {
        const int wb = k & 1;
        const int rb = wb ^ 1;

        // ======== phase 1: stream A MFMAs for step k (h_A(k-1)) ========
        s8v AhA[2], AlA[2];
        #pragma unroll
        for (int c = 0; c < 2; ++c) {
            AhA[c] = *(const s8v*)&sAHh[rb][col][32 * c + quad * 8];
            AlA[c] = *(const s8v*)&sAHl[rb][col][32 * c + quad * 8];
        }
        f4v afA0 = {0.f,0.f,0.f,0.f}, afA1 = {0.f,0.f,0.f,0.f};
        afA0 = __builtin_amdgcn_mfma_f32_16x16x32_bf16(AhA[0], Ff[0], afA0, 0, 0, 0);
        afA0 = __builtin_amdgcn_mfma_f32_16x16x32_bf16(AlA[0], Ff[0], afA0, 0, 0, 0);
        afA1 = __builtin_amdgcn_mfma_f32_16x16x32_bf16(AhA[1], Ff[1], afA1, 0, 0, 0);
        afA1 = __builtin_amdgcn_mfma_f32_16x16x32_bf16(AlA[1], Ff[1], afA1, 0, 0, 0);
        f4v accA[4];
        #pragma unroll
        for (int g = 0; g < 4; ++g) {
            f4v a = {0.f, 0.f, 0.f, 0.f};
            #pragma unroll
            for (int c = 0; c < 2; ++c) {
                a = __builtin_amdgcn_mfma_f32_16x16x32_bf16(AhA[c], Bh[g][c], a, 0, 0, 0);
                a = __builtin_amdgcn_mfma_f32_16x16x32_bf16(AlA[c], Bh[g][c], a, 0, 0, 0);
                a = __builtin_amdgcn_mfma_f32_16x16x32_bf16(AhA[c], Bl[g][c], a, 0, 0, 0);
            }
            accA[g] = a;
        }

        // ======== phase 2: stream B VALU for step k-1 (accB ready) ========
        if (k > 0) {
            // alpha_B(k-2): afB from prev iter, hB regs still h_B(k-2)
            #pragma unroll
            for (int r = 0; r < 2; ++r) {
                float tot = afB0[r] + afB1[r] + fab;
                float al = __expf(tanh_f(tot));
                asB[r] += al;
                gaB[r] = fmaf(al, hB[r], gaB[r]);
            }
            // gates_B(k-1)
            f2v xrB = *(const f2v*)&sXT[k - 1][8 + rrow];
            #pragma unroll
            for (int r = 0; r < 2; ++r) {
                float xv = xrB[r];
                float jp = accB[0][r] + fmaf(xv, u_j, cbj);
                float ip = accB[1][r] + fmaf(xv, u_i, cbi);
                float fp = accB[2][r] + fmaf(xv, u_f, cbf);
                float op = accB[3][r] + fmaf(xv, u_o, cbo);
                cB[r] = fmaf(cB[r], sig_f(fp), sig_f(ip) * tanh_f(jp));
                hB[r] = sig_f(op) * tanh_f(cB[r]);
            }
            // write h_B(k-1) -> bufB[(k-1)&1] = rb
            #pragma unroll
            for (int r = 0; r < 2; ++r) {
                float hv = hB[r];
                uint u = __float_as_uint(hv);
                uint hb = u & 0xFFFF0000u;
                float lo = hv - __uint_as_float(hb);
                sBHh[rb][mrow + r][n] = (u16)(u >> 16);
                sBHl[rb][mrow + r][n] = (u16)f2bf(lo);
            }
        }

        __syncthreads();   // h_B(k-1) visible

        // ======== phase 4: stream B MFMAs for step k (h_B(k-1)) ========
        s8v AhB[2], AlB[2];
        #pragma unroll
        for (int c = 0; c < 2; ++c) {
            AhB[c] = *(const s8v*)&sBHh[rb][col][32 * c + quad * 8];
            AlB[c] = *(const s8v*)&sBHl[rb][col][32 * c + quad * 8];
        }
        afB0 = (f4v){0.f,0.f,0.f,0.f};
        afB1 = (f4v){0.f,0.f,0.f,0.f};
        afB0 = __builtin_amdgcn_mfma_f32_16x16x32_bf16(AhB[0], Ff[0], afB0, 0, 0, 0);
        afB0 = __builtin_amdgcn_mfma_f32_16x16x32_bf16(AlB[0], Ff[0], afB0, 0, 0, 0);
        afB1 = __builtin_amdgcn_mfma_f32_16x16x32_bf16(AhB[1], Ff[1], afB1, 0, 0, 0);
        afB1 = __builtin_amdgcn_mfma_f32_16x16x32_bf16(AlB[1], Ff[1], afB1, 0, 0, 0);
        #pragma unroll
        for (int g = 0; g < 4; ++g) {
            f4v a = {0.f, 0.f, 0.f, 0.f};
            #pragma unroll
            for (int c = 0; c < 2; ++c) {
                a = __builtin_amdgcn_mfma_f32_16x16x32_bf16(AhB[c], Bh[g][c], a, 0, 0, 0);
                a = __builtin_amdgcn_mfma_f32_16x16x32_bf16(AlB[c], Bh[g][c], a, 0, 0, 0);
                a = __builtin_amdgcn_mfma_f32_16x16x32_bf16(AhB[c], Bl[g][c], a, 0, 0, 0);
            }
            accB[g] = a;
        }

        // ======== phase 5: stream A VALU for step k (accA drained) ========
        // alpha_A(k-1): afA from phase 1, hA regs still h_A(k-1)
        #pragma unroll
        for (int r = 0; r < 2; ++r) {
            float tot = afA0[r] + afA1[r] + fab;
            float al = __expf(tanh_f(tot));
            asA[r] += al;
            gaA[r] = fmaf(al, hA[r], gaA[r]);
        }
        // gates_A(k)
        f2v xrA = *(const f2v*)&sXT[k][rrow];
        #pragma unroll
        for (int r = 0; r < 2; ++r) {
            float xv = xrA[r];
            float jp = accA[0][r] + fmaf(xv, u_j, cbj);
            float ip = accA[1][r] + fmaf(xv, u_i, cbi);
            float fp = accA[2][r] + fmaf(xv, u_f, cbf);
            float op = accA[3][r] + fmaf(xv, u_o, cbo);
            cA[r] = fmaf(cA[r], sig_f(fp), sig_f(ip) * tanh_f(jp));
            hA[r] = sig_f(op) * tanh_f(cA[r]);
        }
        // write h_A(k) -> bufA[k&1] = wb
        #pragma unroll
        for (int r = 0; r < 2; ++r) {
            float hv = hA[r];
            uint u = __float_as_uint(hv);
            uint hb = u & 0xFFFF0000u;
            float lo = hv - __uint_as_float(hb);
            sAHh[wb][mrow + r][n] = (u16)(u >> 16);
            sAHl[wb][mrow + r][n] = (u16)f2bf(lo);
        }

        __syncthreads();   // h_A(k) visible for next iter phase 1
    }

    // ======== epilogue: finish stream B step T-1 ========
    {
        // alpha_B(T-2): afB from k=511 phase 4, hB regs = h_B(T-2)
        #pragma unroll
        for (int r = 0; r < 2; ++r) {
            float tot = afB0[r] + afB1[r] + fab;
            float al = __expf(tanh_f(tot));
            asB[r] += al;
            gaB[r] = fmaf(al, hB[r], gaB[r]);
        }
        // gates_B(T-1)
        f2v xrB = *(const f2v*)&sXT[T_LEN - 1][8 + rrow];
        #pragma unroll
        for (int r = 0; r < 2; ++r) {
            float xv = xrB[r];
            float jp = accB[0][r] + fmaf(xv, u_j, cbj);
            float ip = accB[1][r] + fmaf(xv, u_i, cbi);
            float fp = accB[2][r] + fmaf(xv, u_f, cbf);
            float op = accB[3][r] + fmaf(xv, u_o, cbo);
            cB[r] = fmaf(cB[r], sig_f(fp), sig_f(ip) * tanh_f(jp));
            hB[r] = sig_f(op) * tanh_f(cB[r]);
        }
        // write h_B(T-1) -> bufB[1] for the drain read
        #pragma unroll
        for (int r = 0; r < 2; ++r) {
            float hv = hB[r];
            uint u = __float_as_uint(hv);
            uint hb = u & 0xFFFF0000u;
            float lo = hv - __uint_as_float(hb);
            sBHh[1][mrow + r][n] = (u16)(u >> 16);
            sBHl[1][mrow + r][n] = (u16)f2bf(lo);
        }
    }
    __syncthreads();

    // ======== drain alpha(T-1) for BOTH streams (h(T-1) in buf 1) ========
    {
        s8v Ah[2], Al[2];
        #pragma unroll
        for (int c = 0; c < 2; ++c) {
            Ah[c] = *(const s8v*)&sAHh[1][col][32 * c + quad * 8];
            Al[c] = *(const s8v*)&sAHl[1][col][32 * c + quad * 8];
        }
        f4v a0 = {0.f,0.f,0.f,0.f}, a1 = {0.f,0.f,0.f,0.f};
        a0 = __builtin_amdgcn_mfma_f32_16x16x32_bf16(Ah[0], Ff[0], a0, 0, 0, 0);
        a0 = __builtin_amdgcn_mfma_f32_16x16x32_bf16(Al[0], Ff[0], a0, 0, 0, 0);
        a1 = __builtin_amdgcn_mfma_f32_16x16x32_bf16(Ah[1], Ff[1], a1, 0, 0, 0);
        a1 = __builtin_amdgcn_mfma_f32_16x16x32_bf16(Al[1], Ff[1], a1, 0, 0, 0);
        #pragma unroll
        for (int r = 0; r < 2; ++r) {
            float tot = a0[r] + a1[r] + fab;
            float al = __expf(tanh_f(tot));
            asA[r] += al;
            gaA[r] = fmaf(al, hA[r], gaA[r]);
        }
    }
    {
        s8v Ah[2], Al[2];
        #pragma unroll
        for (int c = 0; c < 2; ++c) {
            Ah[c] = *(const s8v*)&sBHh[1][col][32 * c + quad * 8];
            Al[c] = *(const s8v*)&sBHl[1][col][32 * c + quad * 8];
        }
        f4v a0 = {0.f,0.f,0.f,0.f}, a1 = {0.f,0.f,0.f,0.f};
        a0 = __builtin_amdgcn_mfma_f32_16x16x32_bf16(Ah[0], Ff[0], a0, 0, 0, 0);
        a0 = __builtin_amdgcn_mfma_f32_16x16x32_bf16(Al[0], Ff[0], a0, 0, 0, 0);
        a1 = __builtin_amdgcn_mfma_f32_16x16x32_bf16(Ah[1], Ff[1], a1, 0, 0, 0);
        a1 = __builtin_amdgcn_mfma_f32_16x16x32_bf16(Al[1], Ff[1], a1, 0, 0, 0);
        #pragma unroll
        for (int r = 0; r < 2; ++r) {
            float tot = a0[r] + a1[r] + fab;
            float al = __expf(tanh_f(tot));
            asB[r] += al;
            gaB[r] = fmaf(al, hB[r], gaB[r]);
        }
    }

    // ======== epilogue: mu, beta per (row, d), 4 rows per lane ========
    const float pwa = Pw[n],  pwb = Pw[64 + n];
    const float fwa = Fbw[n], fwb = Fbw[64 + n];
    float pmA[2], pvA[2], pmB[2], pvB[2];
    #pragma unroll
    for (int r = 0; r < 2; ++r) {
        float gnA = gaA[r] * rcp_f(asA[r]);
        pmA[r] = fmaf(gnA, pwa, hA[r] * pwb);
        pvA[r] = fmaf(gnA, fwa, hA[r] * fwb);
        float gnB = gaB[r] * rcp_f(asB[r]);
        pmB[r] = fmaf(gnB, pwa, hB[r] * pwb);
        pvB[r] = fmaf(gnB, fwa, hB[r] * fwb);
        pmA[r] += __shfl_xor(pmA[r], 1); pmA[r] += __shfl_xor(pmA[r], 2);
        pmA[r] += __shfl_xor(pmA[r], 4); pmA[r] += __shfl_xor(pmA[r], 8);
        pvA[r] += __shfl_xor(pvA[r], 1); pvA[r] += __shfl_xor(pvA[r], 2);
        pvA[r] += __shfl_xor(pvA[r], 4); pvA[r] += __shfl_xor(pvA[r], 8);
        pmB[r] += __shfl_xor(pmB[r], 1); pmB[r] += __shfl_xor(pmB[r], 2);
        pmB[r] += __shfl_xor(pmB[r], 4); pmB[r] += __shfl_xor(pmB[r], 8);
        pvB[r] += __shfl_xor(pvB[r], 1); pvB[r] += __shfl_xor(pvB[r], 2);
        pvB[r] += __shfl_xor(pvB[r], 4); pvB[r] += __shfl_xor(pvB[r], 8);
    }
    if (col == 0) {
        #pragma unroll
        for (int r = 0; r < 2; ++r) {
            sPS[rrow + r][wg]     = pmA[r];
            sPV[rrow + r][wg]     = pvA[r];
            sPS[8 + rrow + r][wg] = pmB[r];
            sPV[8 + rrow + r][wg] = pvB[r];
        }
    }
    __syncthreads();
    if (tid < R_PAIR) {
        int r = tid;
        f4v a  = *(const f4v*)&sPS[r][0];
        f4v b2 = *(const f4v*)&sPV[r][0];
        float mu = a[0] + a[1] + a[2] + a[3] + Pb[0];
        float bt = __expf(tanh_f(b2[0] + b2[1] + b2[2] + b2[3] + Fbb[0]));
        wmu  [(r0 + r) * D_DIM + d] = mu;
        wbeta[(r0 + r) * D_DIM + d] = bt;
    }
}

// beta softmax over d + weighted sum -> out[b]
__global__ void imv_finalize(const float* __restrict__ wmu,
                             const float* __restrict__ wbeta,
                             float* __restrict__ out)
{
    int b = blockIdx.x * 64 + threadIdx.x;
    if (b >= B_ALL) return;
    float s1 = 0.f, s2 = 0.f;
    for (int d = 0; d < D_DIM; ++d) {
        float be = wbeta[b * D_DIM + d];
        s1 = fmaf(be, wmu[b * D_DIM + d], s1);
        s2 += be;
    }
    out[b] = s1 / s2;
}

extern "C" void kernel_launch(void* const* d_in, const int* in_sizes, int n_in,
                              void* d_out, int out_size, void* d_ws, size_t ws_size,
                              hipStream_t stream)
{
    const float* x   = (const float*)d_in[0];
    const float* U_j = (const float*)d_in[1];
    const float* U_i = (const float*)d_in[2];
    const float* U_f = (const float*)d_in[3];
    const float* U_o = (const float*)d_in[4];
    const float* W_j = (const float*)d_in[5];
    const float* W_i = (const float*)d_in[6];
    const float* W_f = (const float*)d_in[7];
    const float* W_o = (const float*)d_in[8];
    const float* b_j = (const float*)d_in[9];
    const float* b_i = (const float*)d_in[10];
    const float* b_f = (const float*)d_in[11];
    const float* b_o = (const float*)d_in[12];
    const float* Fan  = (const float*)d_in[13];
    const float* Fanb = (const float*)d_in[14];
    const float* Fbw  = (const float*)d_in[15];
    const float* Fbb  = (const float*)d_in[16];
    const float* Phw  = (const float*)d_in[17];
    const float* Phb  = (const float*)d_in[18];

    float* wmu   = (float*)d_ws;
    float* wbeta = wmu + B_ALL * D_DIM;

    imv_lstm_scan<<<dim3(256), dim3(256), 0, stream>>>(
        x, U_j, U_i, U_f, U_o, W_j, W_i, W_f, W_o,
        b_j, b_i, b_f, b_o, Fan, Fanb, Fbw, Fbb, Phw, Phb,
        wmu, wbeta);

    imv_finalize<<<dim3(2), dim3(64), 0, stream>>>(wmu, wbeta, (float*)d_out);
}

// Round 10
// 547.128 us; speedup vs baseline: 1.1162x; 1.1162x over previous
//
#include <hip/hip_runtime.h>

#define T_LEN 512
#define D_DIM 32
#define N_DIM 64
#define B_ALL 128
#define R_TILE 8      // real batch rows per block (per stream; M=16 MFMA)
#define M_DIM 16      // MFMA M dimension
#define HSTR 72       // ushort row stride for h planes: 16B-aligned, bank-spread

typedef short s8v __attribute__((ext_vector_type(8)));   // 8 bf16 (4 VGPRs)
typedef float f4v __attribute__((ext_vector_type(4)));   // MFMA C/D
typedef float f2v __attribute__((ext_vector_type(2)));
typedef unsigned int uint;
typedef unsigned short u16;

__device__ __forceinline__ float rcp_f(float x) {
#if __has_builtin(__builtin_amdgcn_rcpf)
    return __builtin_amdgcn_rcpf(x);
#else
    return 1.0f / x;
#endif
}
__device__ __forceinline__ float tanh_f(float x) {
    float e = __expf(2.0f * x);
    return 1.0f - 2.0f * rcp_f(e + 1.0f);
}
__device__ __forceinline__ float sig_f(float x) {
    return rcp_f(1.0f + __expf(-x));
}
__device__ __forceinline__ uint f2bf(float f) {   // fp32 -> bf16 bits, RNE
    uint u = __float_as_uint(f);
    return (u + 0x7FFFu + ((u >> 16) & 1u)) >> 16;
}
__device__ __forceinline__ s8v pack4(uint a, uint b, uint c, uint d_) {
    union { uint u[4]; s8v v; } x;
    x.u[0] = a; x.u[1] = b; x.u[2] = c; x.u[3] = d_;
    return x.v;
}

// R10: ROLE-SPLIT WAVE PAIRS, BARRIER-ENFORCED ANTI-PHASE.
// Evidence: R7 pipes serialize (MfmaUtil+VALUBusy=101%, wall=sum of phases);
// R8 drift-stagger decays; R9/R4 in-wave dual-stream can't feed two pipes
// from one wave. The working mechanism is m114: TWO waves on one SIMD
// issuing to different pipes. Block = d-pair x 8 rows, 512 thr (8 waves),
// grid 256 = 1 block/CU, 2 waves/SIMD. Stream s = ((wv>>2)^wv)&1 puts one
// S0-wave + one S1-wave on EVERY SIMD under either wave->SIMD mapping
// (round-robin {i,i+4} or consecutive {2i,2i+1}). Per iteration:
//   Phase I : S0 = MFMA(k)      | S1 = VALU(k-1)+h-write   -> barrier
//   Phase II: S1 = MFMA(k)      | S0 = VALU(k)+h-write     -> barrier
// Every instant: one wave feeds matrix pipe, one feeds VALU pipe; the
// barrier re-locks anti-phase each phase. Per-wave work identical to R7
// (28 MFMA + same VALU; own-d W-frags only). S1 runs one step skewed
// (acc/af live across barriers); tail drained in epilogue. Alpha stays
// MFMA-folded with as-init=-exp(tanh(fab)) cancelling the spurious t=-1
// term. Arithmetic per (row,d) identical to R7.
// NOTE: C-fold of x*U+b into MFMA C-in regressed (R5/R6) - keep acc=0.
__global__ void __launch_bounds__(512, 1)
imv_lstm_scan(const float* __restrict__ x,
              const float* __restrict__ Uj, const float* __restrict__ Ui,
              const float* __restrict__ Uf, const float* __restrict__ Uo,
              const float* __restrict__ Wj, const float* __restrict__ Wi,
              const float* __restrict__ Wf, const float* __restrict__ Wo,
              const float* __restrict__ bj, const float* __restrict__ bi_,
              const float* __restrict__ bf_, const float* __restrict__ bo,
              const float* __restrict__ Fa, const float* __restrict__ Fab,
              const float* __restrict__ Fbw, const float* __restrict__ Fbb,
              const float* __restrict__ Pw, const float* __restrict__ Pb,
              float* __restrict__ wmu, float* __restrict__ wbeta)
{
    __shared__ float sXT[2][T_LEN][R_TILE];    // 32 KB, [stream][t][r]
    __shared__ u16   sHh[2][2][M_DIM][HSTR];   // 9.2 KB, [stream][buf][Mrow][k]
    __shared__ u16   sHl[2][2][M_DIM][HSTR];   // 9.2 KB
    __shared__ float sPS[2][R_TILE][4];        // epilogue mu partials
    __shared__ float sPV[2][R_TILE][4];        // epilogue beta partials

    const int tid  = threadIdx.x;
    const int lane = tid & 63;
    const int wv   = tid >> 6;                 // 0..7
    const int s    = ((wv >> 2) ^ wv) & 1;     // stream/role (SIMD-pair safe)
    const int ng   = wv >> 1;                  // n-group 0..3 within stream
    const int quad = lane >> 4;                // 0..3
    const int col  = lane & 15;
    const int d0   = (blockIdx.x & 15) * 2;    // d-pair base
    const int rt   = blockIdx.x >> 4;          // 0..15
    const int r0   = rt * R_TILE;
    const int d    = d0 + s;                   // this wave's d
    const int n    = ng * 16 + col;            // this lane's n
    const int mrow = quad * 4;                 // first M row of lane's 2 rows
    const int rrow = quad * 2;                 // first real row of lane's 2

    // ---- stage x transposed for both d: sXT[dd][t][r] ----
    for (int i = tid; i < 2 * R_TILE * T_LEN; i += 512) {
        int dd = i >> 12, rem = i & 4095;
        int t = rem >> 3, r = rem & 7;
        sXT[dd][t][r] = x[((size_t)(r0 + r) * T_LEN + t) * D_DIM + d0 + dd];
    }
    // ---- h0 = 0 (both streams, both buffers) ----
    for (int i = tid; i < 2 * 2 * M_DIM * HSTR; i += 512) {
        ((u16*)sHh)[i] = 0; ((u16*)sHl)[i] = 0;
    }

    // ---- W fragments for THIS wave's d only: Bh/Bl[gate][k-chunk] ----
    s8v Bh[4][2], Bl[4][2];
    #pragma unroll
    for (int g = 0; g < 4; ++g) {
        const float* Wg = (g == 0 ? Wj : g == 1 ? Wi : g == 2 ? Wf : Wo)
                          + (size_t)d * (N_DIM * N_DIM);
        #pragma unroll
        for (int c = 0; c < 2; ++c) {
            uint hp[4], lp[4];
            #pragma unroll
            for (int jp = 0; jp < 4; ++jp) {
                float w0 = Wg[(32 * c + quad * 8 + 2 * jp + 0) * N_DIM + n];
                float w1 = Wg[(32 * c + quad * 8 + 2 * jp + 1) * N_DIM + n];
                uint u0 = __float_as_uint(w0), u1 = __float_as_uint(w1);
                uint h0b = u0 & 0xFFFF0000u, h1b = u1 & 0xFFFF0000u;
                float l0 = w0 - __uint_as_float(h0b);
                float l1 = w1 - __uint_as_float(h1b);
                hp[jp] = (u0 >> 16) | h1b;
                lp[jp] = f2bf(l0) | (f2bf(l1) << 16);
            }
            Bh[g][c] = pack4(hp[0], hp[1], hp[2], hp[3]);
            Bl[g][c] = pack4(lp[0], lp[1], lp[2], lp[3]);
        }
    }

    // ---- fan-vector B fragment (col-replicated bf16(fan), own d) ----
    s8v Ff[2];
    #pragma unroll
    for (int c = 0; c < 2; ++c) {
        uint p[4];
        #pragma unroll
        for (int jp = 0; jp < 4; ++jp) {
            float f0 = Fa[d * N_DIM + 32 * c + quad * 8 + 2 * jp + 0];
            float f1 = Fa[d * N_DIM + 32 * c + quad * 8 + 2 * jp + 1];
            p[jp] = f2bf(f0) | (f2bf(f1) << 16);
        }
        Ff[c] = pack4(p[0], p[1], p[2], p[3]);
    }

    const int dn = d * N_DIM + n;
    const float u_j = Uj[dn], u_i = Ui[dn], u_f = Uf[dn], u_o = Uo[dn];
    const float cbj = bj[dn], cbi = bi_[dn], cbf = bf_[dn], cbo = bo[dn];
    const float fab = Fab[d];

    __syncthreads();

    float c_[2] = {0.f, 0.f};
    float h_[2] = {0.f, 0.f};
    float ga[2] = {0.f, 0.f};
    const float al_m1 = __expf(tanh_f(fab));
    float as[2] = {-al_m1, -al_m1};

    f4v acc[4];                                  // own-stream pending MFMA out
    f4v af0 = {0.f,0.f,0.f,0.f}, af1 = {0.f,0.f,0.f,0.f};

    // MFMA role: read h(own, buf) -> af (alpha logits) + acc (4 gates)
    auto do_mfma = [&](int buf) {
        s8v Ah[2], Al[2];
        #pragma unroll
        for (int c = 0; c < 2; ++c) {
            Ah[c] = *(const s8v*)&sHh[s][buf][col][32 * c + quad * 8];
            Al[c] = *(const s8v*)&sHl[s][buf][col][32 * c + quad * 8];
        }
        f4v a0 = {0.f,0.f,0.f,0.f}, a1 = {0.f,0.f,0.f,0.f};
        a0 = __builtin_amdgcn_mfma_f32_16x16x32_bf16(Ah[0], Ff[0], a0, 0, 0, 0);
        a0 = __builtin_amdgcn_mfma_f32_16x16x32_bf16(Al[0], Ff[0], a0, 0, 0, 0);
        a1 = __builtin_amdgcn_mfma_f32_16x16x32_bf16(Ah[1], Ff[1], a1, 0, 0, 0);
        a1 = __builtin_amdgcn_mfma_f32_16x16x32_bf16(Al[1], Ff[1], a1, 0, 0, 0);
        af0 = a0; af1 = a1;
        #pragma unroll
        for (int g = 0; g < 4; ++g) {
            f4v a = {0.f, 0.f, 0.f, 0.f};
            #pragma unroll
            for (int c = 0; c < 2; ++c) {
                a = __builtin_amdgcn_mfma_f32_16x16x32_bf16(Ah[c], Bh[g][c], a, 0, 0, 0);
                a = __builtin_amdgcn_mfma_f32_16x16x32_bf16(Al[c], Bh[g][c], a, 0, 0, 0);
                a = __builtin_amdgcn_mfma_f32_16x16x32_bf16(Ah[c], Bl[g][c], a, 0, 0, 0);
            }
            acc[g] = a;
        }
    };

    // VALU role for step t: consume alpha(t-1) (old h_ regs + saved af),
    // gates(t) from saved acc, h update, write h(t) to own planes[buf].
    auto do_valu = [&](int t, int buf) {
        #pragma unroll
        for (int r = 0; r < 2; ++r) {
            float tot = af0[r] + af1[r] + fab;
            float al = __expf(tanh_f(tot));
            as[r] += al;
            ga[r] = fmaf(al, h_[r], ga[r]);
        }
        f2v xr = *(const f2v*)&sXT[s][t][rrow];
        #pragma unroll
        for (int r = 0; r < 2; ++r) {
            float xv = xr[r];
            float jp = acc[0][r] + fmaf(xv, u_j, cbj);
            float ip = acc[1][r] + fmaf(xv, u_i, cbi);
            float fp = acc[2][r] + fmaf(xv, u_f, cbf);
            float op = acc[3][r] + fmaf(xv, u_o, cbo);
            c_[r] = fmaf(c_[r], sig_f(fp), sig_f(ip) * tanh_f(jp));
            h_[r] = sig_f(op) * tanh_f(c_[r]);
        }
        #pragma unroll
        for (int r = 0; r < 2; ++r) {
            float hv = h_[r];
            uint u = __float_as_uint(hv);
            uint hb = u & 0xFFFF0000u;
            float lo = hv - __uint_as_float(hb);
            sHh[s][buf][mrow + r][n] = (u16)(u >> 16);
            sHl[s][buf][mrow + r][n] = (u16)f2bf(lo);
        }
    };

    #pragma unroll 2
    for (int k = 0; k < T_LEN; ++k) {
        const int wb = k & 1;        // h(k) buffer
        const int rb = wb ^ 1;       // h(k-1) buffer

        // Phase I: S0 -> MFMA(k) [reads h_S0(k-1), buf rb];
        //          S1 -> VALU(k-1) [writes h_S1(k-1) to buf rb]
        if (s == 0)      do_mfma(rb);
        else if (k > 0)  do_valu(k - 1, rb);
        __syncthreads();

        // Phase II: S1 -> MFMA(k) [reads h_S1(k-1), buf rb];
        //           S0 -> VALU(k) [writes h_S0(k) to buf wb]
        if (s == 0)      do_valu(k, wb);
        else             do_mfma(rb);
        __syncthreads();
    }

    // ---- S1 tail: VALU(T-1) -> h_S1(T-1) into buf (T-1)&1 = 1 ----
    if (s == 1) do_valu(T_LEN - 1, 1);
    __syncthreads();

    // ---- drain alpha(T-1) for own stream: h(T-1) in buf 1 ----
    {
        s8v Ah[2], Al[2];
        #pragma unroll
        for (int c = 0; c < 2; ++c) {
            Ah[c] = *(const s8v*)&sHh[s][1][col][32 * c + quad * 8];
            Al[c] = *(const s8v*)&sHl[s][1][col][32 * c + quad * 8];
        }
        f4v a0 = {0.f,0.f,0.f,0.f}, a1 = {0.f,0.f,0.f,0.f};
        a0 = __builtin_amdgcn_mfma_f32_16x16x32_bf16(Ah[0], Ff[0], a0, 0, 0, 0);
        a0 = __builtin_amdgcn_mfma_f32_16x16x32_bf16(Al[0], Ff[0], a0, 0, 0, 0);
        a1 = __builtin_amdgcn_mfma_f32_16x16x32_bf16(Ah[1], Ff[1], a1, 0, 0, 0);
        a1 = __builtin_amdgcn_mfma_f32_16x16x32_bf16(Al[1], Ff[1], a1, 0, 0, 0);
        #pragma unroll
        for (int r = 0; r < 2; ++r) {
            float tot = a0[r] + a1[r] + fab;
            float al = __expf(tanh_f(tot));
            as[r] += al;
            ga[r] = fmaf(al, h_[r], ga[r]);
        }
    }

    // ---- epilogue: mu, beta per (row, own d) ----
    const float pwa = Pw[n],  pwb = Pw[64 + n];
    const float fwa = Fbw[n], fwb = Fbw[64 + n];
    float pm[2], pv[2];
    #pragma unroll
    for (int r = 0; r < 2; ++r) {
        float gn = ga[r] * rcp_f(as[r]);
        pm[r] = fmaf(gn, pwa, h_[r] * pwb);
        pv[r] = fmaf(gn, fwa, h_[r] * fwb);
        pm[r] += __shfl_xor(pm[r], 1); pm[r] += __shfl_xor(pm[r], 2);
        pm[r] += __shfl_xor(pm[r], 4); pm[r] += __shfl_xor(pm[r], 8);
        pv[r] += __shfl_xor(pv[r], 1); pv[r] += __shfl_xor(pv[r], 2);
        pv[r] += __shfl_xor(pv[r], 4); pv[r] += __shfl_xor(pv[r], 8);
    }
    if (col == 0) {
        #pragma unroll
        for (int r = 0; r < 2; ++r) {
            sPS[s][rrow + r][ng] = pm[r];
            sPV[s][rrow + r][ng] = pv[r];
        }
    }
    __syncthreads();
    if (tid < 2 * R_TILE) {
        int rr = tid & 7, ss = tid >> 3;
        f4v a  = *(const f4v*)&sPS[ss][rr][0];
        f4v b2 = *(const f4v*)&sPV[ss][rr][0];
        float mu = a[0] + a[1] + a[2] + a[3] + Pb[0];
        float bt = __expf(tanh_f(b2[0] + b2[1] + b2[2] + b2[3] + Fbb[0]));
        wmu  [(r0 + rr) * D_DIM + d0 + ss] = mu;
        wbeta[(r0 + rr) * D_DIM + d0 + ss] = bt;
    }
}

// beta softmax over d + weighted sum -> out[b]
__global__ void imv_finalize(const float* __restrict__ wmu,
                             const float* __restrict__ wbeta,
                             float* __restrict__ out)
{
    int b = blockIdx.x * 64 + threadIdx.x;
    if (b >= B_ALL) return;
    float s1 = 0.f, s2 = 0.f;
    for (int d = 0; d < D_DIM; ++d) {
        float be = wbeta[b * D_DIM + d];
        s1 = fmaf(be, wmu[b * D_DIM + d], s1);
        s2 += be;
    }
    out[b] = s1 / s2;
}

extern "C" void kernel_launch(void* const* d_in, const int* in_sizes, int n_in,
                              void* d_out, int out_size, void* d_ws, size_t ws_size,
                              hipStream_t stream)
{
    const float* x   = (const float*)d_in[0];
    const float* U_j = (const float*)d_in[1];
    const float* U_i = (const float*)d_in[2];
    const float* U_f = (const float*)d_in[3];
    const float* U_o = (const float*)d_in[4];
    const float* W_j = (const float*)d_in[5];
    const float* W_i = (const float*)d_in[6];
    const float* W_f = (const float*)d_in[7];
    const float* W_o = (const float*)d_in[8];
    const float* b_j = (const float*)d_in[9];
    const float* b_i = (const float*)d_in[10];
    const float* b_f = (const float*)d_in[11];
    const float* b_o = (const float*)d_in[12];
    const float* Fan  = (const float*)d_in[13];
    const float* Fanb = (const float*)d_in[14];
    const float* Fbw  = (const float*)d_in[15];
    const float* Fbb  = (const float*)d_in[16];
    const float* Phw  = (const float*)d_in[17];
    const float* Phb  = (const float*)d_in[18];

    float* wmu   = (float*)d_ws;
    float* wbeta = wmu + B_ALL * D_DIM;

    imv_lstm_scan<<<dim3(256), dim3(512), 0, stream>>>(
        x, U_j, U_i, U_f, U_o, W_j, W_i, W_f, W_o,
        b_j, b_i, b_f, b_o, Fan, Fanb, Fbw, Fbb, Phw, Phb,
        wmu, wbeta);

    imv_finalize<<<dim3(2), dim3(64), 0, stream>>>(wmu, wbeta, (float*)d_out);
}

// Round 11
// 480.586 us; speedup vs baseline: 1.2708x; 1.1385x over previous
//
#include <hip/hip_runtime.h>

#define T_LEN 512
#define D_DIM 32
#define N_DIM 64
#define B_ALL 128
#define R_TILE 8      // real batch rows per block (M=16 MFMA, rows permuted)
#define M_DIM 16      // MFMA M dimension
#define HSTR 72       // ushort row stride for h planes: 16B-aligned, bank-spread

typedef _Float16 h8v __attribute__((ext_vector_type(8)));  // 8 f16 (4 VGPRs)
typedef float f4v __attribute__((ext_vector_type(4)));     // MFMA C/D
typedef float f2v __attribute__((ext_vector_type(2)));
typedef unsigned int uint;
typedef unsigned short u16;

__device__ __forceinline__ float rcp_f(float x) {
#if __has_builtin(__builtin_amdgcn_rcpf)
    return __builtin_amdgcn_rcpf(x);
#else
    return 1.0f / x;
#endif
}
__device__ __forceinline__ float tanh_f(float x) {
    float e = __expf(2.0f * x);
    return 1.0f - 2.0f * rcp_f(e + 1.0f);
}
__device__ __forceinline__ float sig_f(float x) {
    return rcp_f(1.0f + __expf(-x));
}
__device__ __forceinline__ uint f2h2(float a, float b) {   // pack two f16 (RNE)
    union { _Float16 h[2]; uint u; } x;
    x.h[0] = (_Float16)a; x.h[1] = (_Float16)b;
    return x.u;
}
__device__ __forceinline__ u16 f2h1(float a) {             // one f16, bits
    union { _Float16 h; u16 s; } x;
    x.h = (_Float16)a;
    return x.s;
}
__device__ __forceinline__ h8v pack4h(uint a, uint b, uint c, uint d_) {
    union { uint u[4]; h8v v; } x;
    x.u[0] = a; x.u[1] = b; x.u[2] = c; x.u[3] = d_;
    return x.v;
}

// R7 structure (best: 490us): grid 512 (32 d x 16 row-octets) x 256 thr
// (4 waves) -> 2 independent blocks/CU; alpha reduction via fan-vector
// MFMAs; 1 barrier/step; M-row permutation (real row r at M index
// 4*(r>>1)+(r&1), lane (quad,col) owns rows 2quad..+1 in C regs 0,1).
// R11 delta (one unit): FP16 2-TERM INSTEAD OF BF16 3-TERM.
// Evidence: R8/R9/R10 all failed to overlap MFMA and VALU pipes -- wall ==
// MFMA-pipe-time + VALU-pipe-time in every structure tried (R7: 985+1334
// = 2319cy vs wall 2300). So shrink the SUM: fp16 has an 11-bit mantissa,
// so W stored as a SINGLE f16 (residual dropped, err ~W*2^-12) and h kept
// 2-piece (hh = f16(h), hl = f16(h - hh), residual 2^-22) gives preact
// error ~1e-5 rms -- tighter than the bf16 3-term scheme's dropped term.
// Gate MFMAs 24 -> 16, alpha 4 (f16 fan); per-SIMD-step MFMA 1086 -> 776cy.
// Everything else byte-identical to R7. absmax moves off 4.77e-7
// (expected ~1e-5..1e-4, still orders under threshold).
// NOTE: C-fold of x*U+b into MFMA C-in regressed (R5/R6) - keep acc=0.
__global__ void __launch_bounds__(256, 2)
imv_lstm_scan(const float* __restrict__ x,
              const float* __restrict__ Uj, const float* __restrict__ Ui,
              const float* __restrict__ Uf, const float* __restrict__ Uo,
              const float* __restrict__ Wj, const float* __restrict__ Wi,
              const float* __restrict__ Wf, const float* __restrict__ Wo,
              const float* __restrict__ bj, const float* __restrict__ bi_,
              const float* __restrict__ bf_, const float* __restrict__ bo,
              const float* __restrict__ Fa, const float* __restrict__ Fab,
              const float* __restrict__ Fbw, const float* __restrict__ Fbb,
              const float* __restrict__ Pw, const float* __restrict__ Pb,
              float* __restrict__ wmu, float* __restrict__ wbeta)
{
    __shared__ float sXT[T_LEN][R_TILE];     // 16 KB, [t][r]
    __shared__ u16   sHh[2][M_DIM][HSTR];    // 4.5 KB, h hi f16, [buf][Mrow][k]
    __shared__ u16   sHl[2][M_DIM][HSTR];    // 4.5 KB, h lo f16
    __shared__ float sPS[R_TILE][4];         // epilogue mu partials
    __shared__ float sPV[R_TILE][4];         // epilogue beta partials

    const int tid  = threadIdx.x;
    const int lane = tid & 63;
    const int wg   = tid >> 6;               // 0..3 (n-group)
    const int quad = lane >> 4;              // 0..3
    const int col  = lane & 15;
    const int d    = blockIdx.x & 31;
    const int rt   = blockIdx.x >> 5;        // 0..15
    const int r0   = rt * R_TILE;
    const int n    = wg * 16 + col;          // this lane's n
    const int mrow = quad * 4;               // first M row of lane's 2 rows
    const int rrow = quad * 2;               // first real row of lane's 2

    // ---- stage x transposed: sXT[t][r] ----
    for (int i = tid; i < R_TILE * T_LEN; i += 256) {
        int t = i >> 3, r = i & 7;
        sXT[t][r] = x[((size_t)(r0 + r) * T_LEN + t) * D_DIM + d];
    }
    // ---- h0 = 0 (zero both buffers; unwritten M rows stay 0 forever) ----
    for (int i = tid; i < 2 * M_DIM * HSTR; i += 256) {
        ((u16*)sHh)[i] = 0; ((u16*)sHl)[i] = 0;
    }

    // ---- W fragments (single f16 term): Bh[gate][k-chunk] ----
    h8v Bh[4][2];
    #pragma unroll
    for (int g = 0; g < 4; ++g) {
        const float* Wg = (g == 0 ? Wj : g == 1 ? Wi : g == 2 ? Wf : Wo)
                          + d * (N_DIM * N_DIM);
        #pragma unroll
        for (int c = 0; c < 2; ++c) {
            uint p[4];
            #pragma unroll
            for (int jp = 0; jp < 4; ++jp) {
                float w0 = Wg[(32 * c + quad * 8 + 2 * jp + 0) * N_DIM + n];
                float w1 = Wg[(32 * c + quad * 8 + 2 * jp + 1) * N_DIM + n];
                p[jp] = f2h2(w0, w1);
            }
            Bh[g][c] = pack4h(p[0], p[1], p[2], p[3]);
        }
    }

    // ---- fan-vector B fragment: B[k][col] = f16(fan[k]), col-replicated ->
    //      D[row][col] = sum_k h[row,k]*fan[k] lands in ALL lanes ----
    h8v Ff[2];
    #pragma unroll
    for (int c = 0; c < 2; ++c) {
        uint p[4];
        #pragma unroll
        for (int jp = 0; jp < 4; ++jp) {
            float f0 = Fa[d * N_DIM + 32 * c + quad * 8 + 2 * jp + 0];
            float f1 = Fa[d * N_DIM + 32 * c + quad * 8 + 2 * jp + 1];
            p[jp] = f2h2(f0, f1);
        }
        Ff[c] = pack4h(p[0], p[1], p[2], p[3]);
    }

    const int dn = d * N_DIM + n;
    const float u_j = Uj[dn], u_i = Ui[dn], u_f = Uf[dn], u_o = Uo[dn];
    const float cbj = bj[dn], cbi = bi_[dn], cbf = bf_[dn], cbo = bo[dn];
    const float fab = Fab[d];

    __syncthreads();

    float c_[2] = {0.f, 0.f};
    float h_[2] = {0.f, 0.f};
    float ga[2] = {0.f, 0.f};
    // as init cancels the spurious t=-1 alpha term exactly: at t=0 the
    // A-frags are exactly 0 -> af=0 -> al = exp(tanh(fab)).
    const float al_m1 = __expf(tanh_f(fab));
    float as[2] = {-al_m1, -al_m1};

    #pragma unroll 2
    for (int t = 0; t < T_LEN; ++t) {
        const int wb = t & 1;        // write buffer (h_t)
        const int rb = wb ^ 1;       // read buffer (h_{t-1})

        // ---- A fragments: direct b128 reads, zero unpack ----
        h8v Ah[2], Al[2];
        #pragma unroll
        for (int c = 0; c < 2; ++c) {
            Ah[c] = *(const h8v*)&sHh[rb][col][32 * c + quad * 8];
            Al[c] = *(const h8v*)&sHl[rb][col][32 * c + quad * 8];
        }

        // ---- alpha logit for step t-1 via MFMA (2 independent 2-chains) ----
        f4v af0 = {0.f, 0.f, 0.f, 0.f};
        f4v af1 = {0.f, 0.f, 0.f, 0.f};
        af0 = __builtin_amdgcn_mfma_f32_16x16x32_f16(Ah[0], Ff[0], af0, 0, 0, 0);
        af0 = __builtin_amdgcn_mfma_f32_16x16x32_f16(Al[0], Ff[0], af0, 0, 0, 0);
        af1 = __builtin_amdgcn_mfma_f32_16x16x32_f16(Ah[1], Ff[1], af1, 0, 0, 0);
        af1 = __builtin_amdgcn_mfma_f32_16x16x32_f16(Al[1], Ff[1], af1, 0, 0, 0);

        // ---- 16 gate MFMAs: 4 gates x 2 k-chunks x 2 h-terms ----
        f4v acc[4];
        #pragma unroll
        for (int g = 0; g < 4; ++g) {
            f4v a = {0.f, 0.f, 0.f, 0.f};
            #pragma unroll
            for (int c = 0; c < 2; ++c) {
                a = __builtin_amdgcn_mfma_f32_16x16x32_f16(Ah[c], Bh[g][c], a, 0, 0, 0);
                a = __builtin_amdgcn_mfma_f32_16x16x32_f16(Al[c], Bh[g][c], a, 0, 0, 0);
            }
            acc[g] = a;
        }

        // ---- alpha(t-1): independent of the gate chain, uses OLD h_ ----
        #pragma unroll
        for (int r = 0; r < 2; ++r) {
            float tot = af0[r] + af1[r] + fab;
            float al = __expf(tanh_f(tot));
            as[r] += al;
            ga[r] = fmaf(al, h_[r], ga[r]);
        }

        // ---- stage 3: C regs 0,1 = real rows rrow, rrow+1 at n ----
        f2v xr = *(const f2v*)&sXT[t][rrow];
        #pragma unroll
        for (int r = 0; r < 2; ++r) {
            float xv = xr[r];
            float jp = acc[0][r] + fmaf(xv, u_j, cbj);
            float ip = acc[1][r] + fmaf(xv, u_i, cbi);
            float fp = acc[2][r] + fmaf(xv, u_f, cbf);
            float op = acc[3][r] + fmaf(xv, u_o, cbo);
            c_[r] = fmaf(c_[r], sig_f(fp), sig_f(ip) * tanh_f(jp));
            h_[r] = sig_f(op) * tanh_f(c_[r]);
        }

        // ---- write h_t (hi/lo f16 planes, M rows mrow..mrow+1) ----
        #pragma unroll
        for (int r = 0; r < 2; ++r) {
            float hv = h_[r];
            _Float16 hh = (_Float16)hv;
            float lo = hv - (float)hh;
            union { _Float16 h; u16 s; } xh; xh.h = hh;
            sHh[wb][mrow + r][n] = xh.s;
            sHl[wb][mrow + r][n] = f2h1(lo);
        }

        __syncthreads();   // the ONLY barrier: h_t planes visible
    }

    // ---- drain alpha(T-1): h_{T-1} is in buffer (T-1)&1 = 1 ----
    {
        h8v Ah[2], Al[2];
        #pragma unroll
        for (int c = 0; c < 2; ++c) {
            Ah[c] = *(const h8v*)&sHh[1][col][32 * c + quad * 8];
            Al[c] = *(const h8v*)&sHl[1][col][32 * c + quad * 8];
        }
        f4v a0 = {0.f, 0.f, 0.f, 0.f};
        f4v a1 = {0.f, 0.f, 0.f, 0.f};
        a0 = __builtin_amdgcn_mfma_f32_16x16x32_f16(Ah[0], Ff[0], a0, 0, 0, 0);
        a0 = __builtin_amdgcn_mfma_f32_16x16x32_f16(Al[0], Ff[0], a0, 0, 0, 0);
        a1 = __builtin_amdgcn_mfma_f32_16x16x32_f16(Ah[1], Ff[1], a1, 0, 0, 0);
        a1 = __builtin_amdgcn_mfma_f32_16x16x32_f16(Al[1], Ff[1], a1, 0, 0, 0);
        #pragma unroll
        for (int r = 0; r < 2; ++r) {
            float tot = a0[r] + a1[r] + fab;
            float al = __expf(tanh_f(tot));
            as[r] += al;
            ga[r] = fmaf(al, h_[r], ga[r]);
        }
    }

    // ---- epilogue: mu, beta per (row, d) ----
    const float pwa = Pw[n],  pwb = Pw[64 + n];
    const float fwa = Fbw[n], fwb = Fbw[64 + n];
    float pm[2], pv[2];
    #pragma unroll
    for (int r = 0; r < 2; ++r) {
        float gn = ga[r] * rcp_f(as[r]);
        pm[r] = fmaf(gn, pwa, h_[r] * pwb);
        pv[r] = fmaf(gn, fwa, h_[r] * fwb);
        pm[r] += __shfl_xor(pm[r], 1); pm[r] += __shfl_xor(pm[r], 2);
        pm[r] += __shfl_xor(pm[r], 4); pm[r] += __shfl_xor(pm[r], 8);
        pv[r] += __shfl_xor(pv[r], 1); pv[r] += __shfl_xor(pv[r], 2);
        pv[r] += __shfl_xor(pv[r], 4); pv[r] += __shfl_xor(pv[r], 8);
    }
    if (col == 0) {
        #pragma unroll
        for (int r = 0; r < 2; ++r) {
            sPS[rrow + r][wg] = pm[r];
            sPV[rrow + r][wg] = pv[r];
        }
    }
    __syncthreads();
    if (tid < R_TILE) {
        int r = tid;
        f4v a  = *(const f4v*)&sPS[r][0];
        f4v b2 = *(const f4v*)&sPV[r][0];
        float mu = a[0] + a[1] + a[2] + a[3] + Pb[0];
        float bt = __expf(tanh_f(b2[0] + b2[1] + b2[2] + b2[3] + Fbb[0]));
        wmu  [(r0 + r) * D_DIM + d] = mu;
        wbeta[(r0 + r) * D_DIM + d] = bt;
    }
}

// beta softmax over d + weighted sum -> out[b]
__global__ void imv_finalize(const float* __restrict__ wmu,
                             const float* __restrict__ wbeta,
                             float* __restrict__ out)
{
    int b = blockIdx.x * 64 + threadIdx.x;
    if (b >= B_ALL) return;
    float s1 = 0.f, s2 = 0.f;
    for (int d = 0; d < D_DIM; ++d) {
        float be = wbeta[b * D_DIM + d];
        s1 = fmaf(be, wmu[b * D_DIM + d], s1);
        s2 += be;
    }
    out[b] = s1 / s2;
}

extern "C" void kernel_launch(void* const* d_in, const int* in_sizes, int n_in,
                              void* d_out, int out_size, void* d_ws, size_t ws_size,
                              hipStream_t stream)
{
    const float* x   = (const float*)d_in[0];
    const float* U_j = (const float*)d_in[1];
    const float* U_i = (const float*)d_in[2];
    const float* U_f = (const float*)d_in[3];
    const float* U_o = (const float*)d_in[4];
    const float* W_j = (const float*)d_in[5];
    const float* W_i = (const float*)d_in[6];
    const float* W_f = (const float*)d_in[7];
    const float* W_o = (const float*)d_in[8];
    const float* b_j = (const float*)d_in[9];
    const float* b_i = (const float*)d_in[10];
    const float* b_f = (const float*)d_in[11];
    const float* b_o = (const float*)d_in[12];
    const float* Fan  = (const float*)d_in[13];
    const float* Fanb = (const float*)d_in[14];
    const float* Fbw  = (const float*)d_in[15];
    const float* Fbb  = (const float*)d_in[16];
    const float* Phw  = (const float*)d_in[17];
    const float* Phb  = (const float*)d_in[18];

    float* wmu   = (float*)d_ws;
    float* wbeta = wmu + B_ALL * D_DIM;

    imv_lstm_scan<<<dim3(512), dim3(256), 0, stream>>>(
        x, U_j, U_i, U_f, U_o, W_j, W_i, W_f, W_o,
        b_j, b_i, b_f, b_o, Fan, Fanb, Fbw, Fbb, Phw, Phb,
        wmu, wbeta);

    imv_finalize<<<dim3(2), dim3(64), 0, stream>>>(wmu, wbeta, (float*)d_out);
}

// Round 12
// 408.049 us; speedup vs baseline: 1.4967x; 1.1778x over previous
//
#include <hip/hip_runtime.h>

#define T_LEN 512
#define D_DIM 32
#define N_DIM 64
#define B_ALL 128
#define R_TILE 8      // real batch rows per block (M=16 MFMA, rows permuted)
#define M_DIM 16      // MFMA M dimension
#define HSTR 72       // ushort row stride for h plane: 16B-aligned, bank-spread

typedef _Float16 h8v __attribute__((ext_vector_type(8)));  // 8 f16 (4 VGPRs)
typedef float f4v __attribute__((ext_vector_type(4)));     // MFMA C/D
typedef float f2v __attribute__((ext_vector_type(2)));
typedef unsigned int uint;
typedef unsigned short u16;

__device__ __forceinline__ float rcp_f(float x) {
#if __has_builtin(__builtin_amdgcn_rcpf)
    return __builtin_amdgcn_rcpf(x);
#else
    return 1.0f / x;
#endif
}
__device__ __forceinline__ float tanh_f(float x) {
    float e = __expf(2.0f * x);
    return 1.0f - 2.0f * rcp_f(e + 1.0f);
}
__device__ __forceinline__ float sig_f(float x) {
    return rcp_f(1.0f + __expf(-x));
}
__device__ __forceinline__ uint f2h2(float a, float b) {   // pack two f16 (RNE)
    union { _Float16 h[2]; uint u; } x;
    x.h[0] = (_Float16)a; x.h[1] = (_Float16)b;
    return x.u;
}
__device__ __forceinline__ h8v pack4h(uint a, uint b, uint c, uint d_) {
    union { uint u[4]; h8v v; } x;
    x.u[0] = a; x.u[1] = b; x.u[2] = c; x.u[3] = d_;
    return x.v;
}

// R7/R11 structure (best: 437us): grid 512 (32 d x 16 row-octets) x 256 thr
// (4 waves) -> 2 independent blocks/CU; alpha reduction via fan-vector
// MFMAs; 1 barrier/step; M-row permutation (real row r at M index
// 4*(r>>1)+(r&1), lane (quad,col) owns rows 2quad..+1 in C regs 0,1).
// R12 delta (one unit): SINGLE-F16 H (drop the h_lo residual plane).
// Evidence: wall == MFMA-time + VALU-time in every structure tried (pipes
// serialize; 4x confirmed R7-R10), so shrink the sum. R11 proved the
// output is INSENSITIVE to ~1e-5 preact perturbations (fp16-W move left
// absmax bit-identical at 4.768e-7). h_lo's contribution is the same
// order (~2e-5), so drop it: gate MFMAs 8, alpha 2 -> 10 MFMA/wave-step
// (was 20), A-reads 4->2 ds_read_b128, h-write halves, lo-split VALU gone,
// LDS -4.5KB. Predicted: MFMA 703->~355cy, VALU 1250->~1150, wall
// 2050->~1550-1750cy. h rounding (2^-11 rel) feeds a contractive gate
// recurrence (STD=0.02) -> expected absmax ~1e-6..1e-5, far under thresh.
// NOTE: C-fold of x*U+b into MFMA C-in regressed (R5/R6) - keep acc=0.
__global__ void __launch_bounds__(256, 2)
imv_lstm_scan(const float* __restrict__ x,
              const float* __restrict__ Uj, const float* __restrict__ Ui,
              const float* __restrict__ Uf, const float* __restrict__ Uo,
              const float* __restrict__ Wj, const float* __restrict__ Wi,
              const float* __restrict__ Wf, const float* __restrict__ Wo,
              const float* __restrict__ bj, const float* __restrict__ bi_,
              const float* __restrict__ bf_, const float* __restrict__ bo,
              const float* __restrict__ Fa, const float* __restrict__ Fab,
              const float* __restrict__ Fbw, const float* __restrict__ Fbb,
              const float* __restrict__ Pw, const float* __restrict__ Pb,
              float* __restrict__ wmu, float* __restrict__ wbeta)
{
    __shared__ float sXT[T_LEN][R_TILE];     // 16 KB, [t][r]
    __shared__ u16   sHh[2][M_DIM][HSTR];    // 4.5 KB, h f16, [buf][Mrow][k]
    __shared__ float sPS[R_TILE][4];         // epilogue mu partials
    __shared__ float sPV[R_TILE][4];         // epilogue beta partials

    const int tid  = threadIdx.x;
    const int lane = tid & 63;
    const int wg   = tid >> 6;               // 0..3 (n-group)
    const int quad = lane >> 4;              // 0..3
    const int col  = lane & 15;
    const int d    = blockIdx.x & 31;
    const int rt   = blockIdx.x >> 5;        // 0..15
    const int r0   = rt * R_TILE;
    const int n    = wg * 16 + col;          // this lane's n
    const int mrow = quad * 4;               // first M row of lane's 2 rows
    const int rrow = quad * 2;               // first real row of lane's 2

    // ---- stage x transposed: sXT[t][r] ----
    for (int i = tid; i < R_TILE * T_LEN; i += 256) {
        int t = i >> 3, r = i & 7;
        sXT[t][r] = x[((size_t)(r0 + r) * T_LEN + t) * D_DIM + d];
    }
    // ---- h0 = 0 (zero both buffers; unwritten M rows stay 0 forever) ----
    for (int i = tid; i < 2 * M_DIM * HSTR; i += 256)
        ((u16*)sHh)[i] = 0;

    // ---- W fragments (single f16 term): Bh[gate][k-chunk] ----
    h8v Bh[4][2];
    #pragma unroll
    for (int g = 0; g < 4; ++g) {
        const float* Wg = (g == 0 ? Wj : g == 1 ? Wi : g == 2 ? Wf : Wo)
                          + d * (N_DIM * N_DIM);
        #pragma unroll
        for (int c = 0; c < 2; ++c) {
            uint p[4];
            #pragma unroll
            for (int jp = 0; jp < 4; ++jp) {
                float w0 = Wg[(32 * c + quad * 8 + 2 * jp + 0) * N_DIM + n];
                float w1 = Wg[(32 * c + quad * 8 + 2 * jp + 1) * N_DIM + n];
                p[jp] = f2h2(w0, w1);
            }
            Bh[g][c] = pack4h(p[0], p[1], p[2], p[3]);
        }
    }

    // ---- fan-vector B fragment: B[k][col] = f16(fan[k]), col-replicated ->
    //      D[row][col] = sum_k h[row,k]*fan[k] lands in ALL lanes ----
    h8v Ff[2];
    #pragma unroll
    for (int c = 0; c < 2; ++c) {
        uint p[4];
        #pragma unroll
        for (int jp = 0; jp < 4; ++jp) {
            float f0 = Fa[d * N_DIM + 32 * c + quad * 8 + 2 * jp + 0];
            float f1 = Fa[d * N_DIM + 32 * c + quad * 8 + 2 * jp + 1];
            p[jp] = f2h2(f0, f1);
        }
        Ff[c] = pack4h(p[0], p[1], p[2], p[3]);
    }

    const int dn = d * N_DIM + n;
    const float u_j = Uj[dn], u_i = Ui[dn], u_f = Uf[dn], u_o = Uo[dn];
    const float cbj = bj[dn], cbi = bi_[dn], cbf = bf_[dn], cbo = bo[dn];
    const float fab = Fab[d];

    __syncthreads();

    float c_[2] = {0.f, 0.f};
    float h_[2] = {0.f, 0.f};
    float ga[2] = {0.f, 0.f};
    // as init cancels the spurious t=-1 alpha term exactly: at t=0 the
    // A-frags are exactly 0 -> af=0 -> al = exp(tanh(fab)).
    const float al_m1 = __expf(tanh_f(fab));
    float as[2] = {-al_m1, -al_m1};

    #pragma unroll 2
    for (int t = 0; t < T_LEN; ++t) {
        const int wb = t & 1;        // write buffer (h_t)
        const int rb = wb ^ 1;       // read buffer (h_{t-1})

        // ---- A fragments: 2 direct b128 reads, zero unpack ----
        h8v Ah[2];
        #pragma unroll
        for (int c = 0; c < 2; ++c)
            Ah[c] = *(const h8v*)&sHh[rb][col][32 * c + quad * 8];

        // ---- alpha logit for step t-1 via MFMA (2 independent) ----
        f4v af0 = {0.f, 0.f, 0.f, 0.f};
        f4v af1 = {0.f, 0.f, 0.f, 0.f};
        af0 = __builtin_amdgcn_mfma_f32_16x16x32_f16(Ah[0], Ff[0], af0, 0, 0, 0);
        af1 = __builtin_amdgcn_mfma_f32_16x16x32_f16(Ah[1], Ff[1], af1, 0, 0, 0);

        // ---- 8 gate MFMAs: 4 gates x 2 k-chunks ----
        f4v acc[4];
        #pragma unroll
        for (int g = 0; g < 4; ++g) {
            f4v a = {0.f, 0.f, 0.f, 0.f};
            a = __builtin_amdgcn_mfma_f32_16x16x32_f16(Ah[0], Bh[g][0], a, 0, 0, 0);
            a = __builtin_amdgcn_mfma_f32_16x16x32_f16(Ah[1], Bh[g][1], a, 0, 0, 0);
            acc[g] = a;
        }

        // ---- alpha(t-1): independent of the gate chain, uses OLD h_ ----
        #pragma unroll
        for (int r = 0; r < 2; ++r) {
            float tot = af0[r] + af1[r] + fab;
            float al = __expf(tanh_f(tot));
            as[r] += al;
            ga[r] = fmaf(al, h_[r], ga[r]);
        }

        // ---- stage 3: C regs 0,1 = real rows rrow, rrow+1 at n ----
        f2v xr = *(const f2v*)&sXT[t][rrow];
        #pragma unroll
        for (int r = 0; r < 2; ++r) {
            float xv = xr[r];
            float jp = acc[0][r] + fmaf(xv, u_j, cbj);
            float ip = acc[1][r] + fmaf(xv, u_i, cbi);
            float fp = acc[2][r] + fmaf(xv, u_f, cbf);
            float op = acc[3][r] + fmaf(xv, u_o, cbo);
            c_[r] = fmaf(c_[r], sig_f(fp), sig_f(ip) * tanh_f(jp));
            h_[r] = sig_f(op) * tanh_f(c_[r]);
        }

        // ---- write h_t (single f16 plane, M rows mrow..mrow+1) ----
        #pragma unroll
        for (int r = 0; r < 2; ++r) {
            union { _Float16 h; u16 s; } xh;
            xh.h = (_Float16)h_[r];
            sHh[wb][mrow + r][n] = xh.s;
        }

        __syncthreads();   // the ONLY barrier: h_t plane visible
    }

    // ---- drain alpha(T-1): h_{T-1} is in buffer (T-1)&1 = 1 ----
    {
        h8v Ah[2];
        #pragma unroll
        for (int c = 0; c < 2; ++c)
            Ah[c] = *(const h8v*)&sHh[1][col][32 * c + quad * 8];
        f4v a0 = {0.f, 0.f, 0.f, 0.f};
        f4v a1 = {0.f, 0.f, 0.f, 0.f};
        a0 = __builtin_amdgcn_mfma_f32_16x16x32_f16(Ah[0], Ff[0], a0, 0, 0, 0);
        a1 = __builtin_amdgcn_mfma_f32_16x16x32_f16(Ah[1], Ff[1], a1, 0, 0, 0);
        #pragma unroll
        for (int r = 0; r < 2; ++r) {
            float tot = a0[r] + a1[r] + fab;
            float al = __expf(tanh_f(tot));
            as[r] += al;
            ga[r] = fmaf(al, h_[r], ga[r]);
        }
    }

    // ---- epilogue: mu, beta per (row, d) ----
    const float pwa = Pw[n],  pwb = Pw[64 + n];
    const float fwa = Fbw[n], fwb = Fbw[64 + n];
    float pm[2], pv[2];
    #pragma unroll
    for (int r = 0; r < 2; ++r) {
        float gn = ga[r] * rcp_f(as[r]);
        pm[r] = fmaf(gn, pwa, h_[r] * pwb);
        pv[r] = fmaf(gn, fwa, h_[r] * fwb);
        pm[r] += __shfl_xor(pm[r], 1); pm[r] += __shfl_xor(pm[r], 2);
        pm[r] += __shfl_xor(pm[r], 4); pm[r] += __shfl_xor(pm[r], 8);
        pv[r] += __shfl_xor(pv[r], 1); pv[r] += __shfl_xor(pv[r], 2);
        pv[r] += __shfl_xor(pv[r], 4); pv[r] += __shfl_xor(pv[r], 8);
    }
    if (col == 0) {
        #pragma unroll
        for (int r = 0; r < 2; ++r) {
            sPS[rrow + r][wg] = pm[r];
            sPV[rrow + r][wg] = pv[r];
        }
    }
    __syncthreads();
    if (tid < R_TILE) {
        int r = tid;
        f4v a  = *(const f4v*)&sPS[r][0];
        f4v b2 = *(const f4v*)&sPV[r][0];
        float mu = a[0] + a[1] + a[2] + a[3] + Pb[0];
        float bt = __expf(tanh_f(b2[0] + b2[1] + b2[2] + b2[3] + Fbb[0]));
        wmu  [(r0 + r) * D_DIM + d] = mu;
        wbeta[(r0 + r) * D_DIM + d] = bt;
    }
}

// beta softmax over d + weighted sum -> out[b]
__global__ void imv_finalize(const float* __restrict__ wmu,
                             const float* __restrict__ wbeta,
                             float* __restrict__ out)
{
    int b = blockIdx.x * 64 + threadIdx.x;
    if (b >= B_ALL) return;
    float s1 = 0.f, s2 = 0.f;
    for (int d = 0; d < D_DIM; ++d) {
        float be = wbeta[b * D_DIM + d];
        s1 = fmaf(be, wmu[b * D_DIM + d], s1);
        s2 += be;
    }
    out[b] = s1 / s2;
}

extern "C" void kernel_launch(void* const* d_in, const int* in_sizes, int n_in,
                              void* d_out, int out_size, void* d_ws, size_t ws_size,
                              hipStream_t stream)
{
    const float* x   = (const float*)d_in[0];
    const float* U_j = (const float*)d_in[1];
    const float* U_i = (const float*)d_in[2];
    const float* U_f = (const float*)d_in[3];
    const float* U_o = (const float*)d_in[4];
    const float* W_j = (const float*)d_in[5];
    const float* W_i = (const float*)d_in[6];
    const float* W_f = (const float*)d_in[7];
    const float* W_o = (const float*)d_in[8];
    const float* b_j = (const float*)d_in[9];
    const float* b_i = (const float*)d_in[10];
    const float* b_f = (const float*)d_in[11];
    const float* b_o = (const float*)d_in[12];
    const float* Fan  = (const float*)d_in[13];
    const float* Fanb = (const float*)d_in[14];
    const float* Fbw  = (const float*)d_in[15];
    const float* Fbb  = (const float*)d_in[16];
    const float* Phw  = (const float*)d_in[17];
    const float* Phb  = (const float*)d_in[18];

    float* wmu   = (float*)d_ws;
    float* wbeta = wmu + B_ALL * D_DIM;

    imv_lstm_scan<<<dim3(512), dim3(256), 0, stream>>>(
        x, U_j, U_i, U_f, U_o, W_j, W_i, W_f, W_o,
        b_j, b_i, b_f, b_o, Fan, Fanb, Fbw, Fbb, Phw, Phb,
        wmu, wbeta);

    imv_finalize<<<dim3(2), dim3(64), 0, stream>>>(wmu, wbeta, (float*)d_out);
}